// Round 2
// baseline (835.734 us; speedup 1.0000x reference)
//
#include <hip/hip_runtime.h>

#define NXT 32640   // xlmr tokens
#define NS  16320   // stanza words
#define NE  65280   // edges
#define DD  768
#define GD  256
#define NLAB 5

// ---------------- degree / dinv ----------------
__global__ void k_count_deg(const int* __restrict__ dsts, float* __restrict__ deg) {
    int e = blockIdx.x * 256 + threadIdx.x;
    if (e < NE) atomicAdd(&deg[dsts[e]], 1.0f);
}

__global__ void k_dinv(float* __restrict__ deg) {
    int w = blockIdx.x * 256 + threadIdx.x;
    if (w < NS) deg[w] = rsqrtf(deg[w] + 1.0f);  // +1 self loop
}

// ---------------- partial logits from x (relu(x) @ Wcls[:768]) ----------------
__global__ void k_partial(const float* __restrict__ x, const float* __restrict__ Wcls,
                          float* __restrict__ partial) {
    int token = blockIdx.x * 4 + (threadIdx.x >> 6);
    int lane  = threadIdx.x & 63;
    const float* xr = x + (size_t)token * DD;
    float a0=0.f, a1=0.f, a2=0.f, a3=0.f, a4=0.f;
#pragma unroll
    for (int it = 0; it < 12; ++it) {
        int d = lane + it * 64;
        float v = xr[d];
        v = v > 0.f ? v : 0.f;
        const float* wr = Wcls + (size_t)d * NLAB;
        a0 += v * wr[0]; a1 += v * wr[1]; a2 += v * wr[2]; a3 += v * wr[3]; a4 += v * wr[4];
    }
#pragma unroll
    for (int off = 32; off > 0; off >>= 1) {
        a0 += __shfl_down(a0, off);
        a1 += __shfl_down(a1, off);
        a2 += __shfl_down(a2, off);
        a3 += __shfl_down(a3, off);
        a4 += __shfl_down(a4, off);
    }
    if (lane == 0) {
        float* p = partial + (size_t)token * NLAB;
        p[0]=a0; p[1]=a1; p[2]=a2; p[3]=a3; p[4]=a4;
    }
}

// ---------------- pooled matmul: h0 = pool(x) @ Wc + bc ----------------
#define BM 64
#define BN 64
#define BK 16
__global__ void k_mm_pooled(const float* __restrict__ x, const int* __restrict__ seg,
                            const float* __restrict__ Wc, const float* __restrict__ bc,
                            float* __restrict__ out) {
    __shared__ float As[BM][BK + 1];
    __shared__ float Bs[BK][BN + 1];
    __shared__ int   srow[BM];
    __shared__ int   erow[BM];
    __shared__ float inv[BM];
    int bm = (blockIdx.x / (GD / BN)) * BM;
    int bn = (blockIdx.x % (GD / BN)) * BM; // BN==BM
    int tid = threadIdx.x;
    if (tid < BM) {
        int w = bm + tid;
        int lo = 0, hi = NXT;
        while (lo < hi) { int mid = (lo + hi) >> 1; if (seg[mid] < w) lo = mid + 1; else hi = mid; }
        int s = lo;
        hi = NXT;
        while (lo < hi) { int mid = (lo + hi) >> 1; if (seg[mid] < w + 1) lo = mid + 1; else hi = mid; }
        srow[tid] = s; erow[tid] = lo;
        int c = lo - s;
        inv[tid] = c > 0 ? 1.0f / (float)c : 0.0f;
    }
    __syncthreads();
    int ty = tid >> 4, tx = tid & 15;
    float acc[4][4] = {};
    for (int k0 = 0; k0 < DD; k0 += BK) {
#pragma unroll
        for (int i = 0; i < 4; ++i) {
            int idx = tid + i * 256;
            int r = idx >> 4, k = idx & 15;
            float s = 0.f;
            for (int j = srow[r]; j < erow[r]; ++j) s += x[(size_t)j * DD + k0 + k];
            As[r][k] = s * inv[r];
        }
#pragma unroll
        for (int i = 0; i < 4; ++i) {
            int idx = tid + i * 256;
            int r = idx >> 6, c = idx & 63;
            Bs[r][c] = Wc[(size_t)(k0 + r) * GD + bn + c];
        }
        __syncthreads();
#pragma unroll
        for (int k = 0; k < BK; ++k) {
            float av[4], bv[4];
#pragma unroll
            for (int i = 0; i < 4; ++i) av[i] = As[ty * 4 + i][k];
#pragma unroll
            for (int j = 0; j < 4; ++j) bv[j] = Bs[k][tx * 4 + j];
#pragma unroll
            for (int i = 0; i < 4; ++i)
#pragma unroll
                for (int j = 0; j < 4; ++j) acc[i][j] += av[i] * bv[j];
        }
        __syncthreads();
    }
#pragma unroll
    for (int i = 0; i < 4; ++i) {
        int r = bm + ty * 4 + i;
#pragma unroll
        for (int j = 0; j < 4; ++j) {
            int c = bn + tx * 4 + j;
            out[(size_t)r * GD + c] = acc[i][j] + bc[c];
        }
    }
}

// ---------------- direct matmul: out = A @ B  (A: [NS,K], B: [K,GD]) ----------------
__global__ void k_mm(const float* __restrict__ A, const float* __restrict__ B,
                     float* __restrict__ out, int K) {
    __shared__ float As[BM][BK + 1];
    __shared__ float Bs[BK][BN + 1];
    int bm = (blockIdx.x / (GD / BN)) * BM;
    int bn = (blockIdx.x % (GD / BN)) * BM;
    int tid = threadIdx.x;
    int ty = tid >> 4, tx = tid & 15;
    float acc[4][4] = {};
    for (int k0 = 0; k0 < K; k0 += BK) {
#pragma unroll
        for (int i = 0; i < 4; ++i) {
            int idx = tid + i * 256;
            int r = idx >> 4, k = idx & 15;
            As[r][k] = A[(size_t)(bm + r) * K + k0 + k];
        }
#pragma unroll
        for (int i = 0; i < 4; ++i) {
            int idx = tid + i * 256;
            int r = idx >> 6, c = idx & 63;
            Bs[r][c] = B[(size_t)(k0 + r) * GD + bn + c];
        }
        __syncthreads();
#pragma unroll
        for (int k = 0; k < BK; ++k) {
            float av[4], bv[4];
#pragma unroll
            for (int i = 0; i < 4; ++i) av[i] = As[ty * 4 + i][k];
#pragma unroll
            for (int j = 0; j < 4; ++j) bv[j] = Bs[k][tx * 4 + j];
#pragma unroll
            for (int i = 0; i < 4; ++i)
#pragma unroll
                for (int j = 0; j < 4; ++j) acc[i][j] += av[i] * bv[j];
        }
        __syncthreads();
    }
#pragma unroll
    for (int i = 0; i < 4; ++i) {
        int r = bm + ty * 4 + i;
#pragma unroll
        for (int j = 0; j < 4; ++j)
            out[(size_t)r * GD + bn + tx * 4 + j] = acc[i][j];
    }
}

// ---------------- edge scatter: agg[dst] += hW[src] * dinv[src]*dinv[dst] ----------------
__global__ void k_scatter(const int* __restrict__ ei, const float* __restrict__ hW,
                          const float* __restrict__ dinv, float* __restrict__ agg) {
    int e    = blockIdx.x * 4 + (threadIdx.x >> 6);
    int lane = threadIdx.x & 63;
    int src = ei[e];
    int dst = ei[NE + e];
    float coef = dinv[src] * dinv[dst];
    const float4 v = *(const float4*)&hW[(size_t)src * GD + lane * 4];
    float* ap = &agg[(size_t)dst * GD + lane * 4];
    atomicAdd(ap + 0, v.x * coef);
    atomicAdd(ap + 1, v.y * coef);
    atomicAdd(ap + 2, v.z * coef);
    atomicAdd(ap + 3, v.w * coef);
}

// ---------------- finalize layer: h = relu(agg + hW*dinv^2 + b) ----------------
__global__ void k_finalize(const float* __restrict__ agg, const float* __restrict__ hW,
                           const float* __restrict__ dinv, const float* __restrict__ b,
                           float* __restrict__ hout) {
    int idx = blockIdx.x * 256 + threadIdx.x;
    int w = idx >> 8, c = idx & 255;
    float di = dinv[w];
    float v = agg[idx] + hW[idx] * di * di + b[c];
    hout[idx] = v > 0.f ? v : 0.f;
}

// ---------------- final logits + log_softmax ----------------
__global__ void k_final(const float* __restrict__ h, const float* __restrict__ partial,
                        const int* __restrict__ seg, const int* __restrict__ upos_ids,
                        const float* __restrict__ upos_table, const float* __restrict__ Wcls,
                        const float* __restrict__ bcls, float* __restrict__ out) {
    int token = blockIdx.x * 4 + (threadIdx.x >> 6);
    int lane  = threadIdx.x & 63;
    int w = seg[token];
    const float* hr = h + (size_t)w * GD;
    float acc[NLAB] = {};
#pragma unroll
    for (int it = 0; it < 4; ++it) {
        int c = lane + it * 64;
        float v = hr[c];
        v = v > 0.f ? v : 0.f;
        const float* wr = Wcls + (size_t)(DD + c) * NLAB;
#pragma unroll
        for (int l = 0; l < NLAB; ++l) acc[l] += v * wr[l];
    }
#pragma unroll
    for (int off = 32; off > 0; off >>= 1)
#pragma unroll
        for (int l = 0; l < NLAB; ++l) acc[l] += __shfl_down(acc[l], off);
    if (lane == 0) {
        int u = upos_ids[w];
        float lg[NLAB];
#pragma unroll
        for (int l = 0; l < NLAB; ++l) {
            float a = acc[l] + partial[(size_t)token * NLAB + l] + bcls[l];
#pragma unroll
            for (int p = 0; p < 4; ++p) {
                float pv = upos_table[u * 4 + p];
                pv = pv > 0.f ? pv : 0.f;
                a += pv * Wcls[(size_t)(DD + GD + p) * NLAB + l];
            }
            lg[l] = a;
        }
        float m = lg[0];
#pragma unroll
        for (int l = 1; l < NLAB; ++l) m = fmaxf(m, lg[l]);
        float s = 0.f;
#pragma unroll
        for (int l = 0; l < NLAB; ++l) s += __expf(lg[l] - m);
        float lse = __logf(s) + m;
        float* op = out + (size_t)token * NLAB;
#pragma unroll
        for (int l = 0; l < NLAB; ++l) op[l] = lg[l] - lse;
    }
}

extern "C" void kernel_launch(void* const* d_in, const int* in_sizes, int n_in,
                              void* d_out, int out_size, void* d_ws, size_t ws_size,
                              hipStream_t stream) {
    const float* x          = (const float*)d_in[0];
    const int*   seg        = (const int*)d_in[1];
    const int*   ei         = (const int*)d_in[2];
    const int*   upos_ids   = (const int*)d_in[3];
    const float* Wc         = (const float*)d_in[4];
    const float* bc         = (const float*)d_in[5];
    const float* gcn_W      = (const float*)d_in[6];
    const float* gcn_b      = (const float*)d_in[7];
    const float* upos_table = (const float*)d_in[8];
    const float* Wcls       = (const float*)d_in[9];
    const float* bcls       = (const float*)d_in[10];
    float* out = (float*)d_out;

    float* partial = (float*)d_ws;                 // NXT*5
    float* dinv    = partial + (size_t)NXT * NLAB; // NS
    float* h_cur   = dinv + NS;                    // NS*GD
    float* hW      = h_cur + (size_t)NS * GD;      // NS*GD
    float* agg     = hW + (size_t)NS * GD;         // NS*GD

    hipMemsetAsync(dinv, 0, NS * sizeof(float), stream);
    k_count_deg<<<(NE + 255) / 256, 256, 0, stream>>>(ei + NE, dinv);
    k_dinv<<<(NS + 255) / 256, 256, 0, stream>>>(dinv);

    k_partial<<<NXT / 4, 256, 0, stream>>>(x, Wcls, partial);

    k_mm_pooled<<<(NS / BM) * (GD / BN), 256, 0, stream>>>(x, seg, Wc, bc, h_cur);

    for (int layer = 0; layer < 2; ++layer) {
        k_mm<<<(NS / BM) * (GD / BN), 256, 0, stream>>>(h_cur, gcn_W + (size_t)layer * GD * GD, hW, GD);
        hipMemsetAsync(agg, 0, (size_t)NS * GD * sizeof(float), stream);
        k_scatter<<<NE / 4, 256, 0, stream>>>(ei, hW, dinv, agg);
        k_finalize<<<(NS * GD) / 256, 256, 0, stream>>>(agg, hW, dinv, gcn_b + (size_t)layer * GD, h_cur);
    }

    k_final<<<NXT / 4, 256, 0, stream>>>(h_cur, partial, seg, upos_ids, upos_table, Wcls, bcls, out);
}

// Round 3
// 406.896 us; speedup vs baseline: 2.0539x; 2.0539x over previous
//
#include <hip/hip_runtime.h>

#define NXT 32640   // xlmr tokens
#define NS  16320   // stanza words
#define NE  65280   // edges
#define DD  768
#define GD  256
#define NLAB 5

// ---------------- CSR build ----------------
__global__ void k_count(const int* __restrict__ dsts, int* __restrict__ cnt) {
    int e = blockIdx.x * 256 + threadIdx.x;
    if (e < NE) atomicAdd(&cnt[dsts[e]], 1);
}

// single block, 1024 threads: exclusive scan of cnt[NS] -> off[NS+1], cur[NS]
__global__ void k_scan(const int* __restrict__ cnt, int* __restrict__ off, int* __restrict__ cur) {
    __shared__ int part[1024];
    int t = threadIdx.x;
    int base = t * 16;
    int local[16];
    int s = 0;
    if (base < NS) {
#pragma unroll
        for (int i = 0; i < 16; ++i) { local[i] = s; s += cnt[base + i]; }
    }
    part[t] = s;
    __syncthreads();
    for (int d = 1; d < 1024; d <<= 1) {
        int u = (t >= d) ? part[t - d] : 0;
        __syncthreads();
        part[t] += u;
        __syncthreads();
    }
    int excl = part[t] - s;
    if (base < NS) {
#pragma unroll
        for (int i = 0; i < 16; ++i) {
            int o = excl + local[i];
            off[base + i] = o;
            cur[base + i] = o;
        }
    }
    if (t == 1023) off[NS] = part[1023];
}

__global__ void k_dinv(const int* __restrict__ cnt, float* __restrict__ dinv) {
    int w = blockIdx.x * 256 + threadIdx.x;
    if (w < NS) dinv[w] = rsqrtf((float)cnt[w] + 1.0f);  // +1 self loop
}

__global__ void k_bucket(const int* __restrict__ ei, int* __restrict__ cur,
                         int* __restrict__ csr_src) {
    int e = blockIdx.x * 256 + threadIdx.x;
    if (e < NE) {
        int dst = ei[NE + e];
        int pos = atomicAdd(&cur[dst], 1);
        csr_src[pos] = ei[e];
    }
}

// ---------------- partial logits from x (relu(x) @ Wcls[:768]) ----------------
__global__ void k_partial(const float* __restrict__ x, const float* __restrict__ Wcls,
                          float* __restrict__ partial) {
    int token = blockIdx.x * 4 + (threadIdx.x >> 6);
    int lane  = threadIdx.x & 63;
    const float* xr = x + (size_t)token * DD;
    float a0=0.f, a1=0.f, a2=0.f, a3=0.f, a4=0.f;
#pragma unroll
    for (int it = 0; it < 12; ++it) {
        int d = lane + it * 64;
        float v = xr[d];
        v = v > 0.f ? v : 0.f;
        const float* wr = Wcls + (size_t)d * NLAB;
        a0 += v * wr[0]; a1 += v * wr[1]; a2 += v * wr[2]; a3 += v * wr[3]; a4 += v * wr[4];
    }
#pragma unroll
    for (int off = 32; off > 0; off >>= 1) {
        a0 += __shfl_down(a0, off);
        a1 += __shfl_down(a1, off);
        a2 += __shfl_down(a2, off);
        a3 += __shfl_down(a3, off);
        a4 += __shfl_down(a4, off);
    }
    if (lane == 0) {
        float* p = partial + (size_t)token * NLAB;
        p[0]=a0; p[1]=a1; p[2]=a2; p[3]=a3; p[4]=a4;
    }
}

// ---------------- pooled matmul: h0 = pool(x) @ Wc + bc ----------------
#define BM 64
#define BN 64
#define BK 16
__global__ void k_mm_pooled(const float* __restrict__ x, const int* __restrict__ seg,
                            const float* __restrict__ Wc, const float* __restrict__ bc,
                            float* __restrict__ out) {
    __shared__ float As[BM][BK + 1];
    __shared__ float Bs[BK][BN + 1];
    __shared__ int   srow[BM];
    __shared__ int   erow[BM];
    __shared__ float inv[BM];
    int bm = (blockIdx.x / (GD / BN)) * BM;
    int bn = (blockIdx.x % (GD / BN)) * BM;
    int tid = threadIdx.x;
    if (tid < BM) {
        int w = bm + tid;
        int lo = 0, hi = NXT;
        while (lo < hi) { int mid = (lo + hi) >> 1; if (seg[mid] < w) lo = mid + 1; else hi = mid; }
        int s = lo;
        hi = NXT;
        while (lo < hi) { int mid = (lo + hi) >> 1; if (seg[mid] < w + 1) lo = mid + 1; else hi = mid; }
        srow[tid] = s; erow[tid] = lo;
        int c = lo - s;
        inv[tid] = c > 0 ? 1.0f / (float)c : 0.0f;
    }
    __syncthreads();
    int ty = tid >> 4, tx = tid & 15;
    float acc[4][4] = {};
    for (int k0 = 0; k0 < DD; k0 += BK) {
#pragma unroll
        for (int i = 0; i < 4; ++i) {
            int idx = tid + i * 256;
            int r = idx >> 4, k = idx & 15;
            float s = 0.f;
            for (int j = srow[r]; j < erow[r]; ++j) s += x[(size_t)j * DD + k0 + k];
            As[r][k] = s * inv[r];
        }
#pragma unroll
        for (int i = 0; i < 4; ++i) {
            int idx = tid + i * 256;
            int r = idx >> 6, c = idx & 63;
            Bs[r][c] = Wc[(size_t)(k0 + r) * GD + bn + c];
        }
        __syncthreads();
#pragma unroll
        for (int k = 0; k < BK; ++k) {
            float av[4], bv[4];
#pragma unroll
            for (int i = 0; i < 4; ++i) av[i] = As[ty * 4 + i][k];
#pragma unroll
            for (int j = 0; j < 4; ++j) bv[j] = Bs[k][tx * 4 + j];
#pragma unroll
            for (int i = 0; i < 4; ++i)
#pragma unroll
                for (int j = 0; j < 4; ++j) acc[i][j] += av[i] * bv[j];
        }
        __syncthreads();
    }
#pragma unroll
    for (int i = 0; i < 4; ++i) {
        int r = bm + ty * 4 + i;
#pragma unroll
        for (int j = 0; j < 4; ++j) {
            int c = bn + tx * 4 + j;
            out[(size_t)r * GD + c] = acc[i][j] + bc[c];
        }
    }
}

// ---------------- direct matmul: out = A @ B  (A: [NS,K], B: [K,GD]) ----------------
__global__ void k_mm(const float* __restrict__ A, const float* __restrict__ B,
                     float* __restrict__ out, int K) {
    __shared__ float As[BM][BK + 1];
    __shared__ float Bs[BK][BN + 1];
    int bm = (blockIdx.x / (GD / BN)) * BM;
    int bn = (blockIdx.x % (GD / BN)) * BM;
    int tid = threadIdx.x;
    int ty = tid >> 4, tx = tid & 15;
    float acc[4][4] = {};
    for (int k0 = 0; k0 < K; k0 += BK) {
#pragma unroll
        for (int i = 0; i < 4; ++i) {
            int idx = tid + i * 256;
            int r = idx >> 4, k = idx & 15;
            As[r][k] = A[(size_t)(bm + r) * K + k0 + k];
        }
#pragma unroll
        for (int i = 0; i < 4; ++i) {
            int idx = tid + i * 256;
            int r = idx >> 6, c = idx & 63;
            Bs[r][c] = B[(size_t)(k0 + r) * GD + bn + c];
        }
        __syncthreads();
#pragma unroll
        for (int k = 0; k < BK; ++k) {
            float av[4], bv[4];
#pragma unroll
            for (int i = 0; i < 4; ++i) av[i] = As[ty * 4 + i][k];
#pragma unroll
            for (int j = 0; j < 4; ++j) bv[j] = Bs[k][tx * 4 + j];
#pragma unroll
            for (int i = 0; i < 4; ++i)
#pragma unroll
                for (int j = 0; j < 4; ++j) acc[i][j] += av[i] * bv[j];
        }
        __syncthreads();
    }
#pragma unroll
    for (int i = 0; i < 4; ++i) {
        int r = bm + ty * 4 + i;
#pragma unroll
        for (int j = 0; j < 4; ++j)
            out[(size_t)r * GD + bn + tx * 4 + j] = acc[i][j];
    }
}

// ---------------- gather: h[dst] = relu(sum_e coef*hW[src] + hW[dst]*dinv^2 + b) ----------------
__global__ void k_gather(const int* __restrict__ off, const int* __restrict__ csr_src,
                         const float* __restrict__ hW, const float* __restrict__ dinv,
                         const float* __restrict__ b, float* __restrict__ hout) {
    int w    = blockIdx.x * 4 + (threadIdx.x >> 6);
    int lane = threadIdx.x & 63;
    int s = off[w], e = off[w + 1];
    float dw = dinv[w];
    float ax = 0.f, ay = 0.f, az = 0.f, aw = 0.f;
    for (int j = s; j < e; ++j) {
        int src = csr_src[j];
        float coef = dinv[src] * dw;
        const float4 v = *(const float4*)&hW[(size_t)src * GD + lane * 4];
        ax += coef * v.x; ay += coef * v.y; az += coef * v.z; aw += coef * v.w;
    }
    const float4 sv = *(const float4*)&hW[(size_t)w * GD + lane * 4];
    const float4 bv = *(const float4*)&b[lane * 4];
    float c2 = dw * dw;
    float4 r;
    r.x = ax + sv.x * c2 + bv.x;
    r.y = ay + sv.y * c2 + bv.y;
    r.z = az + sv.z * c2 + bv.z;
    r.w = aw + sv.w * c2 + bv.w;
    r.x = r.x > 0.f ? r.x : 0.f;
    r.y = r.y > 0.f ? r.y : 0.f;
    r.z = r.z > 0.f ? r.z : 0.f;
    r.w = r.w > 0.f ? r.w : 0.f;
    *(float4*)&hout[(size_t)w * GD + lane * 4] = r;
}

// ---------------- final logits + log_softmax ----------------
__global__ void k_final(const float* __restrict__ h, const float* __restrict__ partial,
                        const int* __restrict__ seg, const int* __restrict__ upos_ids,
                        const float* __restrict__ upos_table, const float* __restrict__ Wcls,
                        const float* __restrict__ bcls, float* __restrict__ out) {
    int token = blockIdx.x * 4 + (threadIdx.x >> 6);
    int lane  = threadIdx.x & 63;
    int w = seg[token];
    const float* hr = h + (size_t)w * GD;
    float acc[NLAB] = {};
#pragma unroll
    for (int it = 0; it < 4; ++it) {
        int c = lane + it * 64;
        float v = hr[c];
        v = v > 0.f ? v : 0.f;
        const float* wr = Wcls + (size_t)(DD + c) * NLAB;
#pragma unroll
        for (int l = 0; l < NLAB; ++l) acc[l] += v * wr[l];
    }
#pragma unroll
    for (int off = 32; off > 0; off >>= 1)
#pragma unroll
        for (int l = 0; l < NLAB; ++l) acc[l] += __shfl_down(acc[l], off);
    if (lane == 0) {
        int u = upos_ids[w];
        float lg[NLAB];
#pragma unroll
        for (int l = 0; l < NLAB; ++l) {
            float a = acc[l] + partial[(size_t)token * NLAB + l] + bcls[l];
#pragma unroll
            for (int p = 0; p < 4; ++p) {
                float pv = upos_table[u * 4 + p];
                pv = pv > 0.f ? pv : 0.f;
                a += pv * Wcls[(size_t)(DD + GD + p) * NLAB + l];
            }
            lg[l] = a;
        }
        float m = lg[0];
#pragma unroll
        for (int l = 1; l < NLAB; ++l) m = fmaxf(m, lg[l]);
        float s = 0.f;
#pragma unroll
        for (int l = 0; l < NLAB; ++l) s += __expf(lg[l] - m);
        float lse = __logf(s) + m;
        float* op = out + (size_t)token * NLAB;
#pragma unroll
        for (int l = 0; l < NLAB; ++l) op[l] = lg[l] - lse;
    }
}

extern "C" void kernel_launch(void* const* d_in, const int* in_sizes, int n_in,
                              void* d_out, int out_size, void* d_ws, size_t ws_size,
                              hipStream_t stream) {
    const float* x          = (const float*)d_in[0];
    const int*   seg        = (const int*)d_in[1];
    const int*   ei         = (const int*)d_in[2];
    const int*   upos_ids   = (const int*)d_in[3];
    const float* Wc         = (const float*)d_in[4];
    const float* bc         = (const float*)d_in[5];
    const float* gcn_W      = (const float*)d_in[6];
    const float* gcn_b      = (const float*)d_in[7];
    const float* upos_table = (const float*)d_in[8];
    const float* Wcls       = (const float*)d_in[9];
    const float* bcls       = (const float*)d_in[10];
    float* out = (float*)d_out;

    float* partial = (float*)d_ws;                 // NXT*NLAB
    float* dinv    = partial + (size_t)NXT * NLAB; // NS
    float* h_cur   = dinv + NS;                    // NS*GD
    float* hW      = h_cur + (size_t)NS * GD;      // NS*GD
    int*   cnt     = (int*)(hW + (size_t)NS * GD); // NS
    int*   off     = cnt + NS;                     // NS+1
    int*   cur     = off + NS + 1;                 // NS
    int*   csr_src = cur + NS;                     // NE

    hipMemsetAsync(cnt, 0, NS * sizeof(int), stream);
    k_count<<<(NE + 255) / 256, 256, 0, stream>>>(ei + NE, cnt);
    k_scan<<<1, 1024, 0, stream>>>(cnt, off, cur);
    k_dinv<<<(NS + 255) / 256, 256, 0, stream>>>(cnt, dinv);
    k_bucket<<<(NE + 255) / 256, 256, 0, stream>>>(ei, cur, csr_src);

    k_partial<<<NXT / 4, 256, 0, stream>>>(x, Wcls, partial);

    k_mm_pooled<<<(NS / BM) * (GD / BN), 256, 0, stream>>>(x, seg, Wc, bc, h_cur);

    for (int layer = 0; layer < 2; ++layer) {
        k_mm<<<(NS / BM) * (GD / BN), 256, 0, stream>>>(h_cur, gcn_W + (size_t)layer * GD * GD, hW, GD);
        k_gather<<<NS / 4, 256, 0, stream>>>(off, csr_src, hW, dinv, gcn_b + (size_t)layer * GD, h_cur);
    }

    k_final<<<NXT / 4, 256, 0, stream>>>(h_cur, partial, seg, upos_ids, upos_table, Wcls, bcls, out);
}

// Round 4
// 289.087 us; speedup vs baseline: 2.8909x; 1.4075x over previous
//
#include <hip/hip_runtime.h>

#define NXT 32640   // xlmr tokens
#define NS  16320   // stanza words
#define NE  65280   // edges
#define DD  768
#define GD  256
#define NLAB 5

typedef __attribute__((ext_vector_type(8))) short bf16x8;
typedef __attribute__((ext_vector_type(4))) float f32x4;

__device__ inline unsigned short f2b(float f) {  // fp32 -> bf16 RNE
    unsigned int u = __float_as_uint(f);
    unsigned int r = (u + 0x7FFFu + ((u >> 16) & 1u)) >> 16;
    return (unsigned short)r;
}
__device__ inline float b2f(unsigned short h) {
    return __uint_as_float((unsigned int)h << 16);
}

// ---------------- CSR build ----------------
__global__ void k_count(const int* __restrict__ dsts, int* __restrict__ cnt) {
    int e = blockIdx.x * 256 + threadIdx.x;
    if (e < NE) atomicAdd(&cnt[dsts[e]], 1);
}

__global__ void k_scan(const int* __restrict__ cnt, int* __restrict__ off, int* __restrict__ cur) {
    __shared__ int part[1024];
    int t = threadIdx.x;
    int base = t * 16;
    int local[16];
    int s = 0;
    if (base < NS) {
#pragma unroll
        for (int i = 0; i < 16; ++i) { local[i] = s; s += cnt[base + i]; }
    }
    part[t] = s;
    __syncthreads();
    for (int d = 1; d < 1024; d <<= 1) {
        int u = (t >= d) ? part[t - d] : 0;
        __syncthreads();
        part[t] += u;
        __syncthreads();
    }
    int excl = part[t] - s;
    if (base < NS) {
#pragma unroll
        for (int i = 0; i < 16; ++i) {
            int o = excl + local[i];
            off[base + i] = o;
            cur[base + i] = o;
        }
    }
    if (t == 1023) off[NS] = part[1023];
}

__global__ void k_dinv(const int* __restrict__ cnt, float* __restrict__ dinv) {
    int w = blockIdx.x * 256 + threadIdx.x;
    if (w < NS) dinv[w] = rsqrtf((float)cnt[w] + 1.0f);  // +1 self loop
}

__global__ void k_bucket(const int* __restrict__ ei, int* __restrict__ cur,
                         int* __restrict__ csr_src) {
    int e = blockIdx.x * 256 + threadIdx.x;
    if (e < NE) {
        int dst = ei[NE + e];
        int pos = atomicAdd(&cur[dst], 1);
        csr_src[pos] = ei[e];
    }
}

// ---------------- weight convert/transpose: WT[n][k] = bf16(W[k][n]) ----------------
__global__ void k_cvt_t(const float* __restrict__ W, unsigned short* __restrict__ WT,
                        int K, int N) {
    int idx = blockIdx.x * 256 + threadIdx.x;
    if (idx >= K * N) return;
    int k = idx / N, n = idx - k * N;
    WT[(size_t)n * K + k] = f2b(W[idx]);
}

// ---------------- fused x pass: partial logits + pooled stanza (bf16) ----------------
// wave per word; lane covers k = p*256 + lane*4 + i (p=0..2, i=0..3)
__global__ void k_fused_x(const float* __restrict__ x, const int* __restrict__ seg,
                          const float* __restrict__ Wcls, float* __restrict__ partial,
                          unsigned short* __restrict__ stanza) {
    int w    = blockIdx.x * 4 + (threadIdx.x >> 6);
    int lane = threadIdx.x & 63;
    float Wr[3][4][5];
#pragma unroll
    for (int p = 0; p < 3; ++p)
#pragma unroll
        for (int i = 0; i < 4; ++i) {
            int k = p * 256 + lane * 4 + i;
            const float* wp = Wcls + (size_t)k * NLAB;
            Wr[p][i][0] = wp[0]; Wr[p][i][1] = wp[1]; Wr[p][i][2] = wp[2];
            Wr[p][i][3] = wp[3]; Wr[p][i][4] = wp[4];
        }
    // token range of word w (seg sorted)
    int lo = 0, hi = NXT;
    while (lo < hi) { int m = (lo + hi) >> 1; if (seg[m] < w) lo = m + 1; else hi = m; }
    int s = lo;
    hi = NXT;
    int lo2 = s;
    while (lo2 < hi) { int m = (lo2 + hi) >> 1; if (seg[m] < w + 1) lo2 = m + 1; else hi = m; }
    int e = lo2;

    float sum[3][4] = {};
    for (int j = s; j < e; ++j) {
        const float* xr = x + (size_t)j * DD;
        float a0 = 0.f, a1 = 0.f, a2 = 0.f, a3 = 0.f, a4 = 0.f;
#pragma unroll
        for (int p = 0; p < 3; ++p) {
            f32x4 v = *(const f32x4*)&xr[p * 256 + lane * 4];
#pragma unroll
            for (int i = 0; i < 4; ++i) {
                float f = v[i];
                sum[p][i] += f;
                float rf = f > 0.f ? f : 0.f;
                a0 += rf * Wr[p][i][0]; a1 += rf * Wr[p][i][1]; a2 += rf * Wr[p][i][2];
                a3 += rf * Wr[p][i][3]; a4 += rf * Wr[p][i][4];
            }
        }
#pragma unroll
        for (int off = 32; off > 0; off >>= 1) {
            a0 += __shfl_down(a0, off);
            a1 += __shfl_down(a1, off);
            a2 += __shfl_down(a2, off);
            a3 += __shfl_down(a3, off);
            a4 += __shfl_down(a4, off);
        }
        if (lane == 0) {
            float* pp = partial + (size_t)j * NLAB;
            pp[0] = a0; pp[1] = a1; pp[2] = a2; pp[3] = a3; pp[4] = a4;
        }
    }
    float inv = (e > s) ? 1.0f / (float)(e - s) : 0.0f;
#pragma unroll
    for (int p = 0; p < 3; ++p) {
        ushort4 o;
        o.x = f2b(sum[p][0] * inv); o.y = f2b(sum[p][1] * inv);
        o.z = f2b(sum[p][2] * inv); o.w = f2b(sum[p][3] * inv);
        *(ushort4*)&stanza[(size_t)w * DD + p * 256 + lane * 4] = o;
    }
}

// ---------------- MFMA GEMM: out_bf16[M,256] = A_bf16[M,K] @ BT_bf16[256,K]^T (+bias) ----------------
// block: 256 thr = 4 waves, 64 rows/block, full N=256 per wave strip of 16 rows
__global__ __launch_bounds__(256) void k_gemm(const unsigned short* __restrict__ A,
                                              const unsigned short* __restrict__ BT,
                                              const float* __restrict__ bias,
                                              unsigned short* __restrict__ out, int K) {
    int wv = threadIdx.x >> 6, lane = threadIdx.x & 63;
    int m0 = blockIdx.x * 64 + wv * 16;
    int rl = lane & 15;
    int kg = (lane >> 4) * 8;
    const unsigned short* Ap = A + (size_t)(m0 + rl) * K + kg;
    const unsigned short* Bp = BT + (size_t)rl * K + kg;
    f32x4 acc[16] = {};
    for (int k0 = 0; k0 < K; k0 += 32) {
        bf16x8 a = *(const bf16x8*)(Ap + k0);
#pragma unroll
        for (int n = 0; n < 16; ++n) {
            bf16x8 b = *(const bf16x8*)(Bp + (size_t)n * 16 * K + k0);
            acc[n] = __builtin_amdgcn_mfma_f32_16x16x32_bf16(a, b, acc[n], 0, 0, 0);
        }
    }
    int orow = m0 + (lane >> 4) * 4;
#pragma unroll
    for (int n = 0; n < 16; ++n) {
        int col = n * 16 + rl;
        float bv = bias ? bias[col] : 0.f;
#pragma unroll
        for (int r = 0; r < 4; ++r)
            out[(size_t)(orow + r) * GD + col] = f2b(acc[n][r] + bv);
    }
}

// ---------------- gather: h[w] = relu(sum coef*hW[src] + hW[w]*dinv^2 + b), bf16 in/out ----------------
__global__ void k_gather(const int* __restrict__ off, const int* __restrict__ csr_src,
                         const unsigned short* __restrict__ hW, const float* __restrict__ dinv,
                         const float* __restrict__ b, unsigned short* __restrict__ hout) {
    int w    = blockIdx.x * 4 + (threadIdx.x >> 6);
    int lane = threadIdx.x & 63;
    int s = off[w], e = off[w + 1];
    float dw = dinv[w];
    float ax = 0.f, ay = 0.f, az = 0.f, aw = 0.f;
    for (int j = s; j < e; ++j) {
        int src = csr_src[j];
        float c = dinv[src] * dw;
        ushort4 v = *(const ushort4*)&hW[(size_t)src * GD + lane * 4];
        ax += c * b2f(v.x); ay += c * b2f(v.y); az += c * b2f(v.z); aw += c * b2f(v.w);
    }
    ushort4 sv = *(const ushort4*)&hW[(size_t)w * GD + lane * 4];
    f32x4 bv = *(const f32x4*)&b[lane * 4];
    float c2 = dw * dw;
    float rx = ax + b2f(sv.x) * c2 + bv[0];
    float ry = ay + b2f(sv.y) * c2 + bv[1];
    float rz = az + b2f(sv.z) * c2 + bv[2];
    float rw = aw + b2f(sv.w) * c2 + bv[3];
    ushort4 o;
    o.x = f2b(rx > 0.f ? rx : 0.f);
    o.y = f2b(ry > 0.f ? ry : 0.f);
    o.z = f2b(rz > 0.f ? rz : 0.f);
    o.w = f2b(rw > 0.f ? rw : 0.f);
    *(ushort4*)&hout[(size_t)w * GD + lane * 4] = o;
}

// ---------------- final logits + log_softmax ----------------
__global__ void k_final(const unsigned short* __restrict__ h, const float* __restrict__ partial,
                        const int* __restrict__ seg, const int* __restrict__ upos_ids,
                        const float* __restrict__ upos_table, const float* __restrict__ Wcls,
                        const float* __restrict__ bcls, float* __restrict__ out) {
    int token = blockIdx.x * 4 + (threadIdx.x >> 6);
    int lane  = threadIdx.x & 63;
    int w = seg[token];
    ushort4 hv = *(const ushort4*)&h[(size_t)w * GD + lane * 4];
    float vals[4] = {b2f(hv.x), b2f(hv.y), b2f(hv.z), b2f(hv.w)};
    float acc[NLAB] = {};
#pragma unroll
    for (int i = 0; i < 4; ++i) {
        float v = vals[i];
        v = v > 0.f ? v : 0.f;
        const float* wr = Wcls + (size_t)(DD + lane * 4 + i) * NLAB;
#pragma unroll
        for (int l = 0; l < NLAB; ++l) acc[l] += v * wr[l];
    }
#pragma unroll
    for (int off = 32; off > 0; off >>= 1)
#pragma unroll
        for (int l = 0; l < NLAB; ++l) acc[l] += __shfl_down(acc[l], off);
    if (lane == 0) {
        int u = upos_ids[w];
        float lg[NLAB];
#pragma unroll
        for (int l = 0; l < NLAB; ++l) {
            float a = acc[l] + partial[(size_t)token * NLAB + l] + bcls[l];
#pragma unroll
            for (int p = 0; p < 4; ++p) {
                float pv = upos_table[u * 4 + p];
                pv = pv > 0.f ? pv : 0.f;
                a += pv * Wcls[(size_t)(DD + GD + p) * NLAB + l];
            }
            lg[l] = a;
        }
        float m = lg[0];
#pragma unroll
        for (int l = 1; l < NLAB; ++l) m = fmaxf(m, lg[l]);
        float s = 0.f;
#pragma unroll
        for (int l = 0; l < NLAB; ++l) s += __expf(lg[l] - m);
        float lse = __logf(s) + m;
        float* op = out + (size_t)token * NLAB;
#pragma unroll
        for (int l = 0; l < NLAB; ++l) op[l] = lg[l] - lse;
    }
}

extern "C" void kernel_launch(void* const* d_in, const int* in_sizes, int n_in,
                              void* d_out, int out_size, void* d_ws, size_t ws_size,
                              hipStream_t stream) {
    const float* x          = (const float*)d_in[0];
    const int*   seg        = (const int*)d_in[1];
    const int*   ei         = (const int*)d_in[2];
    const int*   upos_ids   = (const int*)d_in[3];
    const float* Wc         = (const float*)d_in[4];
    const float* bc         = (const float*)d_in[5];
    const float* gcn_W      = (const float*)d_in[6];
    const float* gcn_b      = (const float*)d_in[7];
    const float* upos_table = (const float*)d_in[8];
    const float* Wcls       = (const float*)d_in[9];
    const float* bcls       = (const float*)d_in[10];
    float* out = (float*)d_out;

    // workspace layout (16B-aligned chunks first)
    char* ws = (char*)d_ws;
    float* partial          = (float*)ws;            ws += (size_t)NXT * NLAB * 4;   // 652800
    float* dinv             = (float*)ws;            ws += (size_t)NS * 4;           // 65280
    unsigned short* stanza  = (unsigned short*)ws;   ws += (size_t)NS * DD * 2;      // 25067520
    unsigned short* h_bf    = (unsigned short*)ws;   ws += (size_t)NS * GD * 2;      // 8355840
    unsigned short* hW_bf   = (unsigned short*)ws;   ws += (size_t)NS * GD * 2;      // 8355840
    unsigned short* WcT     = (unsigned short*)ws;   ws += (size_t)DD * GD * 2;      // 393216
    unsigned short* WT      = (unsigned short*)ws;   ws += (size_t)2 * GD * GD * 2;  // 262144
    int* cnt                = (int*)ws;              ws += (size_t)NS * 4;
    int* off                = (int*)ws;              ws += (size_t)(NS + 1) * 4;
    int* cur                = (int*)ws;              ws += (size_t)NS * 4;
    int* csr_src            = (int*)ws;

    // CSR build + dinv
    hipMemsetAsync(cnt, 0, NS * sizeof(int), stream);
    k_count<<<(NE + 255) / 256, 256, 0, stream>>>(ei + NE, cnt);
    k_scan<<<1, 1024, 0, stream>>>(cnt, off, cur);
    k_dinv<<<(NS + 255) / 256, 256, 0, stream>>>(cnt, dinv);
    k_bucket<<<(NE + 255) / 256, 256, 0, stream>>>(ei, cur, csr_src);

    // weight conversion (bf16, transposed)
    k_cvt_t<<<(DD * GD + 255) / 256, 256, 0, stream>>>(Wc, WcT, DD, GD);
    k_cvt_t<<<(GD * GD + 255) / 256, 256, 0, stream>>>(gcn_W, WT, GD, GD);
    k_cvt_t<<<(GD * GD + 255) / 256, 256, 0, stream>>>(gcn_W + (size_t)GD * GD, WT + (size_t)GD * GD, GD, GD);

    // single pass over x: partial logits + pooled stanza (bf16)
    k_fused_x<<<NS / 4, 256, 0, stream>>>(x, seg, Wcls, partial, stanza);

    // h0 = stanza @ Wc + bc   (bf16 out)
    k_gemm<<<NS / 64, 256, 0, stream>>>(stanza, WcT, bc, h_bf, DD);

    for (int layer = 0; layer < 2; ++layer) {
        k_gemm<<<NS / 64, 256, 0, stream>>>(h_bf, WT + (size_t)layer * GD * GD, nullptr, hW_bf, GD);
        k_gather<<<NS / 4, 256, 0, stream>>>(off, csr_src, hW_bf, dinv, gcn_b + (size_t)layer * GD, h_bf);
    }

    k_final<<<NXT / 4, 256, 0, stream>>>(h_bf, partial, seg, upos_ids, upos_table, Wcls, bcls, out);
}

// Round 5
// 180.421 us; speedup vs baseline: 4.6321x; 1.6023x over previous
//
#include <hip/hip_runtime.h>

#define NXT 32640   // xlmr tokens
#define NS  16320   // stanza words
#define NE  65280   // edges
#define DD  768
#define GD  256
#define NLAB 5

typedef __attribute__((ext_vector_type(8))) short bf16x8;
typedef __attribute__((ext_vector_type(4))) float f32x4;

__device__ inline unsigned short f2b(float f) {  // fp32 -> bf16 RNE
    unsigned int u = __float_as_uint(f);
    unsigned int r = (u + 0x7FFFu + ((u >> 16) & 1u)) >> 16;
    return (unsigned short)r;
}
__device__ inline float b2f(unsigned short h) {
    return __uint_as_float((unsigned int)h << 16);
}

// ---------------- CSR build ----------------
__global__ void k_count(const int* __restrict__ dsts, int* __restrict__ cnt) {
    int e = blockIdx.x * 256 + threadIdx.x;
    if (e < NE) atomicAdd(&cnt[dsts[e]], 1);
}

__global__ void k_scan(const int* __restrict__ cnt, int* __restrict__ off, int* __restrict__ cur) {
    __shared__ int part[1024];
    int t = threadIdx.x;
    int base = t * 16;
    int local[16];
    int s = 0;
    if (base < NS) {
#pragma unroll
        for (int i = 0; i < 16; ++i) { local[i] = s; s += cnt[base + i]; }
    }
    part[t] = s;
    __syncthreads();
    for (int d = 1; d < 1024; d <<= 1) {
        int u = (t >= d) ? part[t - d] : 0;
        __syncthreads();
        part[t] += u;
        __syncthreads();
    }
    int excl = part[t] - s;
    if (base < NS) {
#pragma unroll
        for (int i = 0; i < 16; ++i) {
            int o = excl + local[i];
            off[base + i] = o;
            cur[base + i] = o;
        }
    }
    if (t == 1023) off[NS] = part[1023];
}

__global__ void k_dinv(const int* __restrict__ cnt, float* __restrict__ dinv) {
    int w = blockIdx.x * 256 + threadIdx.x;
    if (w < NS) dinv[w] = rsqrtf((float)cnt[w] + 1.0f);  // +1 self loop
}

__global__ void k_bucket(const int* __restrict__ ei, int* __restrict__ cur,
                         int* __restrict__ csr_src) {
    int e = blockIdx.x * 256 + threadIdx.x;
    if (e < NE) {
        int dst = ei[NE + e];
        int pos = atomicAdd(&cur[dst], 1);
        csr_src[pos] = ei[e];
    }
}

// ---------------- weight convert/transpose: WT[n][k] = bf16(W[k][n]) ----------------
__global__ void k_cvt_t(const float* __restrict__ W, unsigned short* __restrict__ WT,
                        int K, int N) {
    int idx = blockIdx.x * 256 + threadIdx.x;
    if (idx >= K * N) return;
    int k = idx / N, n = idx - k * N;
    WT[(size_t)n * K + k] = f2b(W[idx]);
}

// ---------------- fused x pass: partial logits + pooled stanza (bf16) ----------------
__global__ void k_fused_x(const float* __restrict__ x, const int* __restrict__ seg,
                          const float* __restrict__ Wcls, float* __restrict__ partial,
                          unsigned short* __restrict__ stanza) {
    int w    = blockIdx.x * 4 + (threadIdx.x >> 6);
    int lane = threadIdx.x & 63;
    float Wr[3][4][5];
#pragma unroll
    for (int p = 0; p < 3; ++p)
#pragma unroll
        for (int i = 0; i < 4; ++i) {
            int k = p * 256 + lane * 4 + i;
            const float* wp = Wcls + (size_t)k * NLAB;
            Wr[p][i][0] = wp[0]; Wr[p][i][1] = wp[1]; Wr[p][i][2] = wp[2];
            Wr[p][i][3] = wp[3]; Wr[p][i][4] = wp[4];
        }
    int lo = 0, hi = NXT;
    while (lo < hi) { int m = (lo + hi) >> 1; if (seg[m] < w) lo = m + 1; else hi = m; }
    int s = lo;
    hi = NXT;
    int lo2 = s;
    while (lo2 < hi) { int m = (lo2 + hi) >> 1; if (seg[m] < w + 1) lo2 = m + 1; else hi = m; }
    int e = lo2;

    float sum[3][4] = {};
    for (int j = s; j < e; ++j) {
        const float* xr = x + (size_t)j * DD;
        float a0 = 0.f, a1 = 0.f, a2 = 0.f, a3 = 0.f, a4 = 0.f;
#pragma unroll
        for (int p = 0; p < 3; ++p) {
            f32x4 v = *(const f32x4*)&xr[p * 256 + lane * 4];
#pragma unroll
            for (int i = 0; i < 4; ++i) {
                float f = v[i];
                sum[p][i] += f;
                float rf = f > 0.f ? f : 0.f;
                a0 += rf * Wr[p][i][0]; a1 += rf * Wr[p][i][1]; a2 += rf * Wr[p][i][2];
                a3 += rf * Wr[p][i][3]; a4 += rf * Wr[p][i][4];
            }
        }
#pragma unroll
        for (int off = 32; off > 0; off >>= 1) {
            a0 += __shfl_down(a0, off);
            a1 += __shfl_down(a1, off);
            a2 += __shfl_down(a2, off);
            a3 += __shfl_down(a3, off);
            a4 += __shfl_down(a4, off);
        }
        if (lane == 0) {
            float* pp = partial + (size_t)j * NLAB;
            pp[0] = a0; pp[1] = a1; pp[2] = a2; pp[3] = a3; pp[4] = a4;
        }
    }
    float inv = (e > s) ? 1.0f / (float)(e - s) : 0.0f;
#pragma unroll
    for (int p = 0; p < 3; ++p) {
        ushort4 o;
        o.x = f2b(sum[p][0] * inv); o.y = f2b(sum[p][1] * inv);
        o.z = f2b(sum[p][2] * inv); o.w = f2b(sum[p][3] * inv);
        *(ushort4*)&stanza[(size_t)w * DD + p * 256 + lane * 4] = o;
    }
}

// ---------------- LDS-staged MFMA GEMM ----------------
// out_bf16[M,256] = A_bf16[M,K] @ BT_bf16[256,K]^T (+bias)
// BM=64, BN=128, BK=32. 256 thr = 4 waves in 2x2 (wr,wc).
// Wave computes 32 rows x 64 cols = 2x4 frags of 16x16.
// LDS fragment-ordered: chunk(group g, kc, rl) = g*64 + kc*16 + rl, 16B chunks.
// gl_lds writes chunk==tid (+256 for B's 2nd half) -> ds_read is base+lane*16.
__global__ __launch_bounds__(256) void k_gemm(const unsigned short* __restrict__ A,
                                              const unsigned short* __restrict__ BT,
                                              const float* __restrict__ bias,
                                              unsigned short* __restrict__ out,
                                              int K, int nbn) {
    __shared__ unsigned short lds[(256 + 512) * 8];  // A: 256 chunks, B: 512 chunks
    const int tid  = threadIdx.x;
    const int lane = tid & 63;
    const int wv   = tid >> 6;
    const int wr   = wv >> 1, wc = wv & 1;
    const int bm   = (blockIdx.x / nbn) * 64;
    const int bn   = (blockIdx.x % nbn) * 128;

    // staging source decode for this thread
    const int ca = tid;                 // A chunk
    const int ga = ca >> 6, wa = ca & 63, kca = wa >> 4, rla = wa & 15;
    const unsigned short* srcA = A + (size_t)(bm + ga * 16 + rla) * K + kca * 8;
    const int cb0 = tid;                // B chunks (two halves)
    const int gb0 = cb0 >> 6, wb0 = cb0 & 63, kcb0 = wb0 >> 4, rlb0 = wb0 & 15;
    const unsigned short* srcB0 = BT + (size_t)(bn + gb0 * 16 + rlb0) * K + kcb0 * 8;
    const int cb1 = 256 + tid;
    const int gb1 = cb1 >> 6, wb1 = cb1 & 63, kcb1 = wb1 >> 4, rlb1 = wb1 & 15;
    const unsigned short* srcB1 = BT + (size_t)(bn + gb1 * 16 + rlb1) * K + kcb1 * 8;

    unsigned short* dstA  = lds + (size_t)tid * 8;
    unsigned short* dstB0 = lds + (size_t)(256 + tid) * 8;
    unsigned short* dstB1 = lds + (size_t)(512 + tid) * 8;

    const bf16x8* fragA = (const bf16x8*)lds + (wr * 2) * 64 + lane;        // +m*64
    const bf16x8* fragB = (const bf16x8*)lds + 256 + (wc * 4) * 64 + lane;  // +n*64

    f32x4 acc[2][4] = {};
    for (int k0 = 0; k0 < K; k0 += 32) {
        __builtin_amdgcn_global_load_lds(srcA + k0, dstA, 16, 0, 0);
        __builtin_amdgcn_global_load_lds(srcB0 + k0, dstB0, 16, 0, 0);
        __builtin_amdgcn_global_load_lds(srcB1 + k0, dstB1, 16, 0, 0);
        __syncthreads();
        bf16x8 a0 = fragA[0], a1 = fragA[64];
        bf16x8 b0 = fragB[0], b1 = fragB[64], b2 = fragB[128], b3 = fragB[192];
        acc[0][0] = __builtin_amdgcn_mfma_f32_16x16x32_bf16(a0, b0, acc[0][0], 0, 0, 0);
        acc[0][1] = __builtin_amdgcn_mfma_f32_16x16x32_bf16(a0, b1, acc[0][1], 0, 0, 0);
        acc[0][2] = __builtin_amdgcn_mfma_f32_16x16x32_bf16(a0, b2, acc[0][2], 0, 0, 0);
        acc[0][3] = __builtin_amdgcn_mfma_f32_16x16x32_bf16(a0, b3, acc[0][3], 0, 0, 0);
        acc[1][0] = __builtin_amdgcn_mfma_f32_16x16x32_bf16(a1, b0, acc[1][0], 0, 0, 0);
        acc[1][1] = __builtin_amdgcn_mfma_f32_16x16x32_bf16(a1, b1, acc[1][1], 0, 0, 0);
        acc[1][2] = __builtin_amdgcn_mfma_f32_16x16x32_bf16(a1, b2, acc[1][2], 0, 0, 0);
        acc[1][3] = __builtin_amdgcn_mfma_f32_16x16x32_bf16(a1, b3, acc[1][3], 0, 0, 0);
        __syncthreads();
    }

    const int rl = lane & 15, rq = lane >> 4;
#pragma unroll
    for (int m = 0; m < 2; ++m) {
        int row0 = bm + wr * 32 + m * 16 + rq * 4;
#pragma unroll
        for (int n = 0; n < 4; ++n) {
            int col = bn + wc * 64 + n * 16 + rl;
            float bv = bias ? bias[col] : 0.f;
#pragma unroll
            for (int r = 0; r < 4; ++r)
                out[(size_t)(row0 + r) * GD + col] = f2b(acc[m][n][r] + bv);
        }
    }
}

// ---------------- gather: h[w] = relu(sum coef*hW[src] + hW[w]*dinv^2 + b), bf16 ----------------
__global__ void k_gather(const int* __restrict__ off, const int* __restrict__ csr_src,
                         const unsigned short* __restrict__ hW, const float* __restrict__ dinv,
                         const float* __restrict__ b, unsigned short* __restrict__ hout) {
    int w    = blockIdx.x * 4 + (threadIdx.x >> 6);
    int lane = threadIdx.x & 63;
    int s = off[w], e = off[w + 1];
    float dw = dinv[w];
    float ax = 0.f, ay = 0.f, az = 0.f, aw = 0.f;
    for (int j = s; j < e; ++j) {
        int src = csr_src[j];
        float c = dinv[src] * dw;
        ushort4 v = *(const ushort4*)&hW[(size_t)src * GD + lane * 4];
        ax += c * b2f(v.x); ay += c * b2f(v.y); az += c * b2f(v.z); aw += c * b2f(v.w);
    }
    ushort4 sv = *(const ushort4*)&hW[(size_t)w * GD + lane * 4];
    f32x4 bv = *(const f32x4*)&b[lane * 4];
    float c2 = dw * dw;
    float rx = ax + b2f(sv.x) * c2 + bv[0];
    float ry = ay + b2f(sv.y) * c2 + bv[1];
    float rz = az + b2f(sv.z) * c2 + bv[2];
    float rw = aw + b2f(sv.w) * c2 + bv[3];
    ushort4 o;
    o.x = f2b(rx > 0.f ? rx : 0.f);
    o.y = f2b(ry > 0.f ? ry : 0.f);
    o.z = f2b(rz > 0.f ? rz : 0.f);
    o.w = f2b(rw > 0.f ? rw : 0.f);
    *(ushort4*)&hout[(size_t)w * GD + lane * 4] = o;
}

// ---------------- final logits + log_softmax ----------------
__global__ void k_final(const unsigned short* __restrict__ h, const float* __restrict__ partial,
                        const int* __restrict__ seg, const int* __restrict__ upos_ids,
                        const float* __restrict__ upos_table, const float* __restrict__ Wcls,
                        const float* __restrict__ bcls, float* __restrict__ out) {
    int token = blockIdx.x * 4 + (threadIdx.x >> 6);
    int lane  = threadIdx.x & 63;
    int w = seg[token];
    ushort4 hv = *(const ushort4*)&h[(size_t)w * GD + lane * 4];
    float vals[4] = {b2f(hv.x), b2f(hv.y), b2f(hv.z), b2f(hv.w)};
    float acc[NLAB] = {};
#pragma unroll
    for (int i = 0; i < 4; ++i) {
        float v = vals[i];
        v = v > 0.f ? v : 0.f;
        const float* wr = Wcls + (size_t)(DD + lane * 4 + i) * NLAB;
#pragma unroll
        for (int l = 0; l < NLAB; ++l) acc[l] += v * wr[l];
    }
#pragma unroll
    for (int off = 32; off > 0; off >>= 1)
#pragma unroll
        for (int l = 0; l < NLAB; ++l) acc[l] += __shfl_down(acc[l], off);
    if (lane == 0) {
        int u = upos_ids[w];
        float lg[NLAB];
#pragma unroll
        for (int l = 0; l < NLAB; ++l) {
            float a = acc[l] + partial[(size_t)token * NLAB + l] + bcls[l];
#pragma unroll
            for (int p = 0; p < 4; ++p) {
                float pv = upos_table[u * 4 + p];
                pv = pv > 0.f ? pv : 0.f;
                a += pv * Wcls[(size_t)(DD + GD + p) * NLAB + l];
            }
            lg[l] = a;
        }
        float m = lg[0];
#pragma unroll
        for (int l = 1; l < NLAB; ++l) m = fmaxf(m, lg[l]);
        float s = 0.f;
#pragma unroll
        for (int l = 0; l < NLAB; ++l) s += __expf(lg[l] - m);
        float lse = __logf(s) + m;
        float* op = out + (size_t)token * NLAB;
#pragma unroll
        for (int l = 0; l < NLAB; ++l) op[l] = lg[l] - lse;
    }
}

extern "C" void kernel_launch(void* const* d_in, const int* in_sizes, int n_in,
                              void* d_out, int out_size, void* d_ws, size_t ws_size,
                              hipStream_t stream) {
    const float* x          = (const float*)d_in[0];
    const int*   seg        = (const int*)d_in[1];
    const int*   ei         = (const int*)d_in[2];
    const int*   upos_ids   = (const int*)d_in[3];
    const float* Wc         = (const float*)d_in[4];
    const float* bc         = (const float*)d_in[5];
    const float* gcn_W      = (const float*)d_in[6];
    const float* gcn_b      = (const float*)d_in[7];
    const float* upos_table = (const float*)d_in[8];
    const float* Wcls       = (const float*)d_in[9];
    const float* bcls       = (const float*)d_in[10];
    float* out = (float*)d_out;

    char* ws = (char*)d_ws;
    float* partial          = (float*)ws;            ws += (size_t)NXT * NLAB * 4;
    float* dinv             = (float*)ws;            ws += (size_t)NS * 4;
    unsigned short* stanza  = (unsigned short*)ws;   ws += (size_t)NS * DD * 2;
    unsigned short* h_bf    = (unsigned short*)ws;   ws += (size_t)NS * GD * 2;
    unsigned short* hW_bf   = (unsigned short*)ws;   ws += (size_t)NS * GD * 2;
    unsigned short* WcT     = (unsigned short*)ws;   ws += (size_t)DD * GD * 2;
    unsigned short* WT      = (unsigned short*)ws;   ws += (size_t)2 * GD * GD * 2;
    int* cnt                = (int*)ws;              ws += (size_t)NS * 4;
    int* off                = (int*)ws;              ws += (size_t)(NS + 1) * 4;
    int* cur                = (int*)ws;              ws += (size_t)NS * 4;
    int* csr_src            = (int*)ws;

    // CSR build + dinv
    hipMemsetAsync(cnt, 0, NS * sizeof(int), stream);
    k_count<<<(NE + 255) / 256, 256, 0, stream>>>(ei + NE, cnt);
    k_scan<<<1, 1024, 0, stream>>>(cnt, off, cur);
    k_dinv<<<(NS + 255) / 256, 256, 0, stream>>>(cnt, dinv);
    k_bucket<<<(NE + 255) / 256, 256, 0, stream>>>(ei, cur, csr_src);

    // weight conversion (bf16, transposed)
    k_cvt_t<<<(DD * GD + 255) / 256, 256, 0, stream>>>(Wc, WcT, DD, GD);
    k_cvt_t<<<(GD * GD + 255) / 256, 256, 0, stream>>>(gcn_W, WT, GD, GD);
    k_cvt_t<<<(GD * GD + 255) / 256, 256, 0, stream>>>(gcn_W + (size_t)GD * GD, WT + (size_t)GD * GD, GD, GD);

    // single pass over x: partial logits + pooled stanza (bf16)
    k_fused_x<<<NS / 4, 256, 0, stream>>>(x, seg, Wcls, partial, stanza);

    // h0 = stanza @ Wc + bc   (bf16 out); grid = (M/64) * (N/128)
    k_gemm<<<(NS / 64) * 2, 256, 0, stream>>>(stanza, WcT, bc, h_bf, DD, 2);

    for (int layer = 0; layer < 2; ++layer) {
        k_gemm<<<(NS / 64) * 2, 256, 0, stream>>>(h_bf, WT + (size_t)layer * GD * GD, nullptr, hW_bf, GD, 2);
        k_gather<<<NS / 4, 256, 0, stream>>>(off, csr_src, hW_bf, dinv, gcn_b + (size_t)layer * GD, h_bf);
    }

    k_final<<<NXT / 4, 256, 0, stream>>>(h_bf, partial, seg, upos_ids, upos_table, Wcls, bcls, out);
}

// Round 6
// 173.805 us; speedup vs baseline: 4.8085x; 1.0381x over previous
//
#include <hip/hip_runtime.h>

#define NXT 32640   // xlmr tokens
#define NS  16320   // stanza words
#define NE  65280   // edges
#define DD  768
#define GD  256
#define NLAB 5

typedef __attribute__((ext_vector_type(8))) short bf16x8;
typedef __attribute__((ext_vector_type(4))) float f32x4;

__device__ inline unsigned short f2b(float f) {  // fp32 -> bf16 RNE
    unsigned int u = __float_as_uint(f);
    unsigned int r = (u + 0x7FFFu + ((u >> 16) & 1u)) >> 16;
    return (unsigned short)r;
}
__device__ inline float b2f(unsigned short h) {
    return __uint_as_float((unsigned int)h << 16);
}

// ---------------- CSR build ----------------
__global__ void k_count(const int* __restrict__ dsts, int* __restrict__ cnt) {
    int e = blockIdx.x * 256 + threadIdx.x;
    if (e < NE) atomicAdd(&cnt[dsts[e]], 1);
}

__global__ void k_scan(const int* __restrict__ cnt, int* __restrict__ off, int* __restrict__ cur) {
    __shared__ int part[1024];
    int t = threadIdx.x;
    int base = t * 16;
    int local[16];
    int s = 0;
    if (base < NS) {
#pragma unroll
        for (int i = 0; i < 16; ++i) { local[i] = s; s += cnt[base + i]; }
    }
    part[t] = s;
    __syncthreads();
    for (int d = 1; d < 1024; d <<= 1) {
        int u = (t >= d) ? part[t - d] : 0;
        __syncthreads();
        part[t] += u;
        __syncthreads();
    }
    int excl = part[t] - s;
    if (base < NS) {
#pragma unroll
        for (int i = 0; i < 16; ++i) {
            int o = excl + local[i];
            off[base + i] = o;
            cur[base + i] = o;
        }
    }
    if (t == 1023) off[NS] = part[1023];
}

__global__ void k_dinv(const int* __restrict__ cnt, float* __restrict__ dinv) {
    int w = blockIdx.x * 256 + threadIdx.x;
    if (w < NS) dinv[w] = rsqrtf((float)cnt[w] + 1.0f);  // +1 self loop
}

__global__ void k_bucket(const int* __restrict__ ei, int* __restrict__ cur,
                         int* __restrict__ csr_src) {
    int e = blockIdx.x * 256 + threadIdx.x;
    if (e < NE) {
        int dst = ei[NE + e];
        int pos = atomicAdd(&cur[dst], 1);
        csr_src[pos] = ei[e];
    }
}

// ---------------- word boundaries from sorted seg ----------------
__global__ void k_bounds(const int* __restrict__ seg, int* __restrict__ wstart) {
    int j = blockIdx.x * 256 + threadIdx.x;
    if (j >= NXT) return;
    int s = seg[j];
    if (j == 0 || seg[j - 1] != s) wstart[s] = j;
    if (j == NXT - 1) wstart[NS] = NXT;
}

// ---------------- weight convert/transpose: WT[n][k] = bf16(W[k][n]) ----------------
__global__ void k_cvt_t(const float* __restrict__ W, unsigned short* __restrict__ WT,
                        int K, int N) {
    int idx = blockIdx.x * 256 + threadIdx.x;
    if (idx >= K * N) return;
    int k = idx / N, n = idx - k * N;
    WT[(size_t)n * K + k] = f2b(W[idx]);
}

// ---------------- Wcls[:768] -> fragment-ordered bf16, cols 5..15 zero ----------------
// WclsF[s*512 + l*8 + i] = col(l&15) < 5 ? bf16(Wcls[(s*32 + (l>>4)*8 + i)*5 + col]) : 0
__global__ void k_cvt_cls(const float* __restrict__ Wcls, unsigned short* __restrict__ WclsF) {
    int idx = blockIdx.x * 256 + threadIdx.x;   // 24*64*8 = 12288
    if (idx >= 24 * 64 * 8) return;
    int i = idx & 7, l = (idx >> 3) & 63, s = idx >> 9;
    int col = l & 15;
    int k = s * 32 + (l >> 4) * 8 + i;
    WclsF[idx] = (col < NLAB) ? f2b(Wcls[(size_t)k * NLAB + col]) : 0;
}

// ---------------- pooled stanza (bf16): wave per word ----------------
__global__ void k_pool(const float* __restrict__ x, const int* __restrict__ wstart,
                       unsigned short* __restrict__ stanza) {
    int w    = blockIdx.x * 4 + (threadIdx.x >> 6);
    int lane = threadIdx.x & 63;
    int s = wstart[w], e = wstart[w + 1];
    float sum[3][4] = {};
    for (int j = s; j < e; ++j) {
        const float* xr = x + (size_t)j * DD + lane * 4;
#pragma unroll
        for (int p = 0; p < 3; ++p) {
            f32x4 v = *(const f32x4*)(xr + p * 256);
            sum[p][0] += v[0]; sum[p][1] += v[1]; sum[p][2] += v[2]; sum[p][3] += v[3];
        }
    }
    float inv = (e > s) ? 1.0f / (float)(e - s) : 0.0f;
#pragma unroll
    for (int p = 0; p < 3; ++p) {
        ushort4 o;
        o.x = f2b(sum[p][0] * inv); o.y = f2b(sum[p][1] * inv);
        o.z = f2b(sum[p][2] * inv); o.w = f2b(sum[p][3] * inv);
        *(ushort4*)&stanza[(size_t)w * DD + p * 256 + lane * 4] = o;
    }
}

// ---------------- partial logits via MFMA: relu(x) @ Wcls[:768] ----------------
// wave per 16-token tile; acc C-layout: col=lane&15, row=(lane>>4)*4+r
__global__ __launch_bounds__(256) void k_logits(const float* __restrict__ x,
                                                const unsigned short* __restrict__ WclsF,
                                                float* __restrict__ partial) {
    int wv = threadIdx.x >> 6, lane = threadIdx.x & 63;
    int tok0 = (blockIdx.x * 4 + wv) * 16;
    int row = lane & 15, kg = (lane >> 4) * 8;
    const float* xp = x + (size_t)(tok0 + row) * DD + kg;
    f32x4 acc = {};
    for (int s = 0; s < 24; ++s) {
        f32x4 v0 = *(const f32x4*)(xp + s * 32);
        f32x4 v1 = *(const f32x4*)(xp + s * 32 + 4);
        bf16x8 a;
#pragma unroll
        for (int i = 0; i < 4; ++i) {
            float f0 = v0[i] > 0.f ? v0[i] : 0.f;
            float f1 = v1[i] > 0.f ? v1[i] : 0.f;
            a[i]     = (short)f2b(f0);
            a[4 + i] = (short)f2b(f1);
        }
        bf16x8 b = *(const bf16x8*)(WclsF + (size_t)s * 512 + lane * 8);
        acc = __builtin_amdgcn_mfma_f32_16x16x32_bf16(a, b, acc, 0, 0, 0);
    }
    if (row < NLAB) {
        int r0 = tok0 + (lane >> 4) * 4;
#pragma unroll
        for (int r = 0; r < 4; ++r)
            partial[(size_t)(r0 + r) * NLAB + row] = acc[r];
    }
}

// ---------------- LDS-staged MFMA GEMM ----------------
// out_bf16[M,256] = A_bf16[M,K] @ BT_bf16[256,K]^T (+bias)
// BM=64, BN=128, BK=32. 256 thr = 4 waves in 2x2 (wr,wc).
__global__ __launch_bounds__(256) void k_gemm(const unsigned short* __restrict__ A,
                                              const unsigned short* __restrict__ BT,
                                              const float* __restrict__ bias,
                                              unsigned short* __restrict__ out,
                                              int K, int nbn) {
    __shared__ unsigned short lds[(256 + 512) * 8];  // A: 256 chunks, B: 512 chunks
    const int tid  = threadIdx.x;
    const int lane = tid & 63;
    const int wv   = tid >> 6;
    const int wr   = wv >> 1, wc = wv & 1;
    const int bm   = (blockIdx.x / nbn) * 64;
    const int bn   = (blockIdx.x % nbn) * 128;

    const int ca = tid;
    const int ga = ca >> 6, wa = ca & 63, kca = wa >> 4, rla = wa & 15;
    const unsigned short* srcA = A + (size_t)(bm + ga * 16 + rla) * K + kca * 8;
    const int cb0 = tid;
    const int gb0 = cb0 >> 6, wb0 = cb0 & 63, kcb0 = wb0 >> 4, rlb0 = wb0 & 15;
    const unsigned short* srcB0 = BT + (size_t)(bn + gb0 * 16 + rlb0) * K + kcb0 * 8;
    const int cb1 = 256 + tid;
    const int gb1 = cb1 >> 6, wb1 = cb1 & 63, kcb1 = wb1 >> 4, rlb1 = wb1 & 15;
    const unsigned short* srcB1 = BT + (size_t)(bn + gb1 * 16 + rlb1) * K + kcb1 * 8;

    unsigned short* dstA  = lds + (size_t)tid * 8;
    unsigned short* dstB0 = lds + (size_t)(256 + tid) * 8;
    unsigned short* dstB1 = lds + (size_t)(512 + tid) * 8;

    const bf16x8* fragA = (const bf16x8*)lds + (wr * 2) * 64 + lane;
    const bf16x8* fragB = (const bf16x8*)lds + 256 + (wc * 4) * 64 + lane;

    f32x4 acc[2][4] = {};
    for (int k0 = 0; k0 < K; k0 += 32) {
        __builtin_amdgcn_global_load_lds(srcA + k0, dstA, 16, 0, 0);
        __builtin_amdgcn_global_load_lds(srcB0 + k0, dstB0, 16, 0, 0);
        __builtin_amdgcn_global_load_lds(srcB1 + k0, dstB1, 16, 0, 0);
        __syncthreads();
        bf16x8 a0 = fragA[0], a1 = fragA[64];
        bf16x8 b0 = fragB[0], b1 = fragB[64], b2 = fragB[128], b3 = fragB[192];
        acc[0][0] = __builtin_amdgcn_mfma_f32_16x16x32_bf16(a0, b0, acc[0][0], 0, 0, 0);
        acc[0][1] = __builtin_amdgcn_mfma_f32_16x16x32_bf16(a0, b1, acc[0][1], 0, 0, 0);
        acc[0][2] = __builtin_amdgcn_mfma_f32_16x16x32_bf16(a0, b2, acc[0][2], 0, 0, 0);
        acc[0][3] = __builtin_amdgcn_mfma_f32_16x16x32_bf16(a0, b3, acc[0][3], 0, 0, 0);
        acc[1][0] = __builtin_amdgcn_mfma_f32_16x16x32_bf16(a1, b0, acc[1][0], 0, 0, 0);
        acc[1][1] = __builtin_amdgcn_mfma_f32_16x16x32_bf16(a1, b1, acc[1][1], 0, 0, 0);
        acc[1][2] = __builtin_amdgcn_mfma_f32_16x16x32_bf16(a1, b2, acc[1][2], 0, 0, 0);
        acc[1][3] = __builtin_amdgcn_mfma_f32_16x16x32_bf16(a1, b3, acc[1][3], 0, 0, 0);
        __syncthreads();
    }

    const int rl = lane & 15, rq = lane >> 4;
#pragma unroll
    for (int m = 0; m < 2; ++m) {
        int row0 = bm + wr * 32 + m * 16 + rq * 4;
#pragma unroll
        for (int n = 0; n < 4; ++n) {
            int col = bn + wc * 64 + n * 16 + rl;
            float bv = bias ? bias[col] : 0.f;
#pragma unroll
            for (int r = 0; r < 4; ++r)
                out[(size_t)(row0 + r) * GD + col] = f2b(acc[m][n][r] + bv);
        }
    }
}

// ---------------- gather: h[w] = relu(sum coef*hW[src] + hW[w]*dinv^2 + b), bf16 ----------------
__global__ void k_gather(const int* __restrict__ off, const int* __restrict__ csr_src,
                         const unsigned short* __restrict__ hW, const float* __restrict__ dinv,
                         const float* __restrict__ b, unsigned short* __restrict__ hout) {
    int w    = blockIdx.x * 4 + (threadIdx.x >> 6);
    int lane = threadIdx.x & 63;
    int s = off[w], e = off[w + 1];
    float dw = dinv[w];
    float ax = 0.f, ay = 0.f, az = 0.f, aw = 0.f;
    for (int j = s; j < e; ++j) {
        int src = csr_src[j];
        float c = dinv[src] * dw;
        ushort4 v = *(const ushort4*)&hW[(size_t)src * GD + lane * 4];
        ax += c * b2f(v.x); ay += c * b2f(v.y); az += c * b2f(v.z); aw += c * b2f(v.w);
    }
    ushort4 sv = *(const ushort4*)&hW[(size_t)w * GD + lane * 4];
    f32x4 bv = *(const f32x4*)&b[lane * 4];
    float c2 = dw * dw;
    float rx = ax + b2f(sv.x) * c2 + bv[0];
    float ry = ay + b2f(sv.y) * c2 + bv[1];
    float rz = az + b2f(sv.z) * c2 + bv[2];
    float rw = aw + b2f(sv.w) * c2 + bv[3];
    ushort4 o;
    o.x = f2b(rx > 0.f ? rx : 0.f);
    o.y = f2b(ry > 0.f ? ry : 0.f);
    o.z = f2b(rz > 0.f ? rz : 0.f);
    o.w = f2b(rw > 0.f ? rw : 0.f);
    *(ushort4*)&hout[(size_t)w * GD + lane * 4] = o;
}

// ---------------- final logits + log_softmax ----------------
__global__ void k_final(const unsigned short* __restrict__ h, const float* __restrict__ partial,
                        const int* __restrict__ seg, const int* __restrict__ upos_ids,
                        const float* __restrict__ upos_table, const float* __restrict__ Wcls,
                        const float* __restrict__ bcls, float* __restrict__ out) {
    int token = blockIdx.x * 4 + (threadIdx.x >> 6);
    int lane  = threadIdx.x & 63;
    int w = seg[token];
    ushort4 hv = *(const ushort4*)&h[(size_t)w * GD + lane * 4];
    float vals[4] = {b2f(hv.x), b2f(hv.y), b2f(hv.z), b2f(hv.w)};
    float acc[NLAB] = {};
#pragma unroll
    for (int i = 0; i < 4; ++i) {
        float v = vals[i];
        v = v > 0.f ? v : 0.f;
        const float* wr = Wcls + (size_t)(DD + lane * 4 + i) * NLAB;
#pragma unroll
        for (int l = 0; l < NLAB; ++l) acc[l] += v * wr[l];
    }
#pragma unroll
    for (int off = 32; off > 0; off >>= 1)
#pragma unroll
        for (int l = 0; l < NLAB; ++l) acc[l] += __shfl_down(acc[l], off);
    if (lane == 0) {
        int u = upos_ids[w];
        float lg[NLAB];
#pragma unroll
        for (int l = 0; l < NLAB; ++l) {
            float a = acc[l] + partial[(size_t)token * NLAB + l] + bcls[l];
#pragma unroll
            for (int p = 0; p < 4; ++p) {
                float pv = upos_table[u * 4 + p];
                pv = pv > 0.f ? pv : 0.f;
                a += pv * Wcls[(size_t)(DD + GD + p) * NLAB + l];
            }
            lg[l] = a;
        }
        float m = lg[0];
#pragma unroll
        for (int l = 1; l < NLAB; ++l) m = fmaxf(m, lg[l]);
        float s = 0.f;
#pragma unroll
        for (int l = 0; l < NLAB; ++l) s += __expf(lg[l] - m);
        float lse = __logf(s) + m;
        float* op = out + (size_t)token * NLAB;
#pragma unroll
        for (int l = 0; l < NLAB; ++l) op[l] = lg[l] - lse;
    }
}

extern "C" void kernel_launch(void* const* d_in, const int* in_sizes, int n_in,
                              void* d_out, int out_size, void* d_ws, size_t ws_size,
                              hipStream_t stream) {
    const float* x          = (const float*)d_in[0];
    const int*   seg        = (const int*)d_in[1];
    const int*   ei         = (const int*)d_in[2];
    const int*   upos_ids   = (const int*)d_in[3];
    const float* Wc         = (const float*)d_in[4];
    const float* bc         = (const float*)d_in[5];
    const float* gcn_W      = (const float*)d_in[6];
    const float* gcn_b      = (const float*)d_in[7];
    const float* upos_table = (const float*)d_in[8];
    const float* Wcls       = (const float*)d_in[9];
    const float* bcls       = (const float*)d_in[10];
    float* out = (float*)d_out;

    char* ws = (char*)d_ws;
    float* partial          = (float*)ws;            ws += (size_t)NXT * NLAB * 4;
    float* dinv             = (float*)ws;            ws += (size_t)NS * 4;
    unsigned short* stanza  = (unsigned short*)ws;   ws += (size_t)NS * DD * 2;
    unsigned short* h_bf    = (unsigned short*)ws;   ws += (size_t)NS * GD * 2;
    unsigned short* hW_bf   = (unsigned short*)ws;   ws += (size_t)NS * GD * 2;
    unsigned short* WcT     = (unsigned short*)ws;   ws += (size_t)DD * GD * 2;
    unsigned short* WT      = (unsigned short*)ws;   ws += (size_t)2 * GD * GD * 2;
    unsigned short* WclsF   = (unsigned short*)ws;   ws += (size_t)24 * 512 * 2;
    int* cnt                = (int*)ws;              ws += (size_t)NS * 4;
    int* off                = (int*)ws;              ws += (size_t)(NS + 1) * 4;
    int* cur                = (int*)ws;              ws += (size_t)NS * 4;
    int* wstart             = (int*)ws;              ws += (size_t)(NS + 1) * 4;
    int* csr_src            = (int*)ws;

    // CSR build + dinv + word bounds
    hipMemsetAsync(cnt, 0, NS * sizeof(int), stream);
    k_count<<<(NE + 255) / 256, 256, 0, stream>>>(ei + NE, cnt);
    k_scan<<<1, 1024, 0, stream>>>(cnt, off, cur);
    k_dinv<<<(NS + 255) / 256, 256, 0, stream>>>(cnt, dinv);
    k_bucket<<<(NE + 255) / 256, 256, 0, stream>>>(ei, cur, csr_src);
    k_bounds<<<(NXT + 255) / 256, 256, 0, stream>>>(seg, wstart);

    // weight conversion (bf16)
    k_cvt_t<<<(DD * GD + 255) / 256, 256, 0, stream>>>(Wc, WcT, DD, GD);
    k_cvt_t<<<(GD * GD + 255) / 256, 256, 0, stream>>>(gcn_W, WT, GD, GD);
    k_cvt_t<<<(GD * GD + 255) / 256, 256, 0, stream>>>(gcn_W + (size_t)GD * GD, WT + (size_t)GD * GD, GD, GD);
    k_cvt_cls<<<(24 * 512 + 255) / 256, 256, 0, stream>>>(Wcls, WclsF);

    // two passes over x (L3-resident)
    k_pool<<<NS / 4, 256, 0, stream>>>(x, wstart, stanza);
    k_logits<<<NXT / 64, 256, 0, stream>>>(x, WclsF, partial);

    // h0 = stanza @ Wc + bc
    k_gemm<<<(NS / 64) * 2, 256, 0, stream>>>(stanza, WcT, bc, h_bf, DD, 2);

    for (int layer = 0; layer < 2; ++layer) {
        k_gemm<<<(NS / 64) * 2, 256, 0, stream>>>(h_bf, WT + (size_t)layer * GD * GD, nullptr, hW_bf, GD, 2);
        k_gather<<<NS / 4, 256, 0, stream>>>(off, csr_src, hW_bf, dinv, gcn_b + (size_t)layer * GD, h_bf);
    }

    k_final<<<NXT / 4, 256, 0, stream>>>(h_bf, partial, seg, upos_ids, upos_table, Wcls, bcls, out);
}